// Round 11
// baseline (324.831 us; speedup 1.0000x reference)
//
#include <hip/hip_runtime.h>
#include <hip/hip_bf16.h>

typedef __hip_bfloat16 bf16;
typedef long long i64;
typedef unsigned long long u64;
typedef __attribute__((ext_vector_type(8))) short short8;
typedef __attribute__((ext_vector_type(4))) float floatx4;

#define NN    50000
#define EE    1600000
#define E2    1650000     // EE + NN self loops
#define FIN   256
#define HD    128         // HEADS*HID
#define NH    4
#define NC    16
#define SLOPE 0.2f
#define K     128         // dst buckets
#define DPB   391         // nodes per bucket (128*391 = 50048 >= NN)
#define CAPB  16384       // per-bucket bin capacity (mean 12891, +30 sigma)
#define CAP   15360       // LDS csr buffer per bucket
#define CH2   2048        // edges per binScatter chunk (8 consecutive per thread)

#define FR_W  36          // fragment row (32 + 4 pad) shorts
#define FW_W  68          // f32 epilogue tile row (64 + 4 pad)

// ---- workspace 4-byte-unit offsets (total ~8.9M dwords = 35.6 MB; 61.6 proven safe) ----
#define OF_FLAGS 0            // 16 ints
#define OF_BCUR  16           // K ints
#define OF_BBASE 144          // K+1 ints
#define OF_RP    304          // NN+1 ints
#define OF_BIN   50308        // u64[K*CAPB]; dead after csrB -> reused as hA/hB
#define OF_HA    50308        // bf16[NN*64]  (alias of bin; 16B aligned)
#define OF_HB    1650308      // bf16[NN*64]
#define OF_CSR   4244612      // E2 ints
#define OF_XQA   5894612      // int8[NN*64] (16B aligned)
#define OF_XQB   6694612      // int8[NN*64]
#define OF_SC    7494612      // f32[NN*2]
#define OF_AS1   7594612      // NN*NH f32
#define OF_AD1   7794612      // NN*NH f32
#define OF_HW2   7994612      // NN*NC f32 (16B aligned)
#define OF_AS2   8794612      // NN f32
#define OF_AD2   8844612      // NN f32

__device__ __forceinline__ float b2f(bf16 v) { return __bfloat162float(v); }
__device__ __forceinline__ float us2f(unsigned short u) {
    return __uint_as_float(((unsigned)u) << 16);
}
__device__ __forceinline__ unsigned short f2us(float f) {   // RNE f32->bf16
    unsigned u = __float_as_uint(f);
    return (unsigned short)((u + 0x7fffu + ((u >> 16) & 1u)) >> 16);
}
__device__ __forceinline__ float lrelu(float v) { return v > 0.f ? v : SLOPE * v; }
__device__ __forceinline__ float sb2f(unsigned u, int sh) {   // signed byte -> float
    return (float)((int)(u << (24 - sh)) >> 24);
}
__device__ __forceinline__ float bpermf(int srcLane, float v) {
    return __int_as_float(__builtin_amdgcn_ds_bpermute(srcLane * 4, __float_as_int(v)));
}
__device__ __forceinline__ int bpermi(int srcLane, int v) {
    return __builtin_amdgcn_ds_bpermute(srcLane * 4, v);
}

template <bool F32>
__device__ __forceinline__ float ldin(const void* p, int i) {
    if (F32) return ((const float*)p)[i];
    return b2f(((const bf16*)p)[i]);
}
template <bool F32>
__device__ __forceinline__ float4 ldin4(const void* p, int i) {
    if (F32) return *(const float4*)((const float*)p + i);
    ushort4 u = *(const ushort4*)((const unsigned short*)p + i);
    float4 r;
    r.x = us2f(u.x); r.y = us2f(u.y); r.z = us2f(u.z); r.w = us2f(u.w);
    return r;
}

__device__ __forceinline__ void edge_sd(const void* ei, int f64, int e, int& s, int& d) {
    if (e >= EE) { s = e - EE; d = s; return; }
    if (f64) {
        s = (int)((const i64*)ei)[e];
        d = (int)((const i64*)ei)[EE + e];
    } else {
        s = ((const int*)ei)[e];
        d = ((const int*)ei)[EE + e];
    }
    s = min(max(s, 0), NN - 1);
    d = min(max(d, 0), NN - 1);
}

// ---------------- detect (proven: picks f32/i32) + bcur init ----------------
__global__ void detect(const void* x, const void* ei, int* flags, int* bcur) {
    __shared__ int cnt[2];
    int t = threadIdx.x;
    if (t < K) bcur[t] = t * CAPB;
    if (t == 0) { cnt[0] = 0; cnt[1] = 0; }
    __syncthreads();
    const unsigned short* xb = (const unsigned short*)x;
    int c0 = 0;
    for (int i = t; i < 4096; i += 256) {
        float v = __uint_as_float(((unsigned)xb[2 * i]) << 16);
        if (!(fabsf(v) < 1e6f)) c0++;
    }
    const i64* e64 = (const i64*)ei;
    int c1 = 0;
    for (int i = t; i < 1024; i += 256) {
        i64 v = e64[i];
        if (v >= 0 && v < NN) c1++;
    }
    atomicAdd(&cnt[0], c0);
    atomicAdd(&cnt[1], c1);
    __syncthreads();
    if (t == 0) {
        flags[0] = (cnt[0] > 400) ? 1 : 0;
        flags[1] = (cnt[1] >= 1000) ? 1 : 0;
    }
}

// single-pass scatter: 8 consecutive edges/thread, int4 edge loads, LDS-histogram ranks
__global__ __launch_bounds__(256) void binScatter(const void* __restrict__ ei,
                                                  const int* __restrict__ flags,
                                                  int* __restrict__ bcur,
                                                  u64* __restrict__ bin) {
    __shared__ int h[K], res[K];
    int t = threadIdx.x;
    int base = blockIdx.x * CH2 + t * 8;
    if (t < K) h[t] = 0;
    __syncthreads();
    int f64 = flags[1];
    int sv[8], dv[8], rk[8];
    int n_ = 0;
    if (!f64 && base + 8 <= EE) {
        const int* es = (const int*)ei;
        int4 a = *(const int4*)&es[base];
        int4 b = *(const int4*)&es[base + 4];
        int4 c = *(const int4*)&es[EE + base];
        int4 g = *(const int4*)&es[EE + base + 4];
        sv[0] = a.x; sv[1] = a.y; sv[2] = a.z; sv[3] = a.w;
        sv[4] = b.x; sv[5] = b.y; sv[6] = b.z; sv[7] = b.w;
        dv[0] = c.x; dv[1] = c.y; dv[2] = c.z; dv[3] = c.w;
        dv[4] = g.x; dv[5] = g.y; dv[6] = g.z; dv[7] = g.w;
#pragma unroll
        for (int i = 0; i < 8; i++) {
            sv[i] = min(max(sv[i], 0), NN - 1);
            dv[i] = min(max(dv[i], 0), NN - 1);
        }
        n_ = 8;
    } else {
        for (int i = 0; i < 8; i++) {
            int e = base + i;
            if (e < E2) {
                int s, d; edge_sd(ei, f64, e, s, d);
                sv[n_] = s; dv[n_] = d; n_++;
            }
        }
    }
#pragma unroll 8
    for (int i = 0; i < n_; i++) rk[i] = atomicAdd(&h[dv[i] / DPB], 1);
    __syncthreads();
    if (t < K) res[t] = h[t] ? atomicAdd(&bcur[t], h[t]) : 0;
    __syncthreads();
#pragma unroll 8
    for (int i = 0; i < n_; i++) {
        int b = dv[i] / DPB;
        int pos = res[b] + rk[i];
        pos = min(pos, (b + 1) * CAPB - 1);   // overflow safety (never hit: +30 sigma)
        bin[pos] = (((u64)(unsigned)dv[i]) << 32) | (unsigned)sv[i];
    }
}

// exclusive scan of actual bucket sizes -> bbase (packed csr layout)
__global__ void bucketScan(const int* __restrict__ bcur, int* __restrict__ bbase) {
    __shared__ int sh[K];
    int t = threadIdx.x;
    int v = min(bcur[t] - t * CAPB, CAPB);
    sh[t] = v;
    __syncthreads();
    for (int off = 1; off < K; off <<= 1) {
        int u = (t >= off) ? sh[t - off] : 0;
        __syncthreads();
        sh[t] += u;
        __syncthreads();
    }
    bbase[t] = sh[t] - v;
    if (t == K - 1) bbase[K] = sh[K - 1];
}

// per-bucket local CSR: per-dst count -> scan -> rp + LDS scatter -> coalesced csr
__global__ __launch_bounds__(256) void csrB(const u64* __restrict__ bin,
                                            const int* __restrict__ bbase,
                                            int* __restrict__ rp, int* __restrict__ csr) {
    __shared__ int cnt[512];
    __shared__ int cur[DPB];
    __shared__ int buf[CAP];     // also reused as scan partials
    int b = blockIdx.x, t = threadIdx.x;
    int d0 = b * DPB;
    int nd = min(DPB, NN - d0);
    int src0 = b * CAPB;
    int base = bbase[b], size = bbase[b + 1] - base;
    cnt[t] = 0; cnt[t + 256] = 0;
    __syncthreads();
    for (int i = t; i < size; i += 256) {
        int d = (int)(bin[src0 + i] >> 32);
        atomicAdd(&cnt[d - d0], 1);
    }
    __syncthreads();
    int a0 = cnt[2 * t], a1 = cnt[2 * t + 1];
    int ps = a0 + a1;
    buf[t] = ps;
    __syncthreads();
    for (int off = 1; off < 256; off <<= 1) {
        int u = (t >= off) ? buf[t - off] : 0;
        __syncthreads();
        buf[t] += u;
        __syncthreads();
    }
    int ex = buf[t] - ps;
    __syncthreads();
    cnt[2 * t] = ex;
    cnt[2 * t + 1] = ex + a0;
    __syncthreads();
    for (int i = t; i < nd; i += 256) {
        rp[d0 + i] = base + cnt[i];
        cur[i] = cnt[i];
    }
    if (b == K - 1 && t == 0) rp[NN] = bbase[K];
    __syncthreads();
    if (size <= CAP) {
        for (int i = t; i < size; i += 256) {
            u64 p = bin[src0 + i];
            int pos = atomicAdd(&cur[(int)(p >> 32) - d0], 1);
            buf[pos] = (int)(unsigned)p;
        }
        __syncthreads();
        for (int i = t; i < size; i += 256) csr[base + i] = buf[i];
    } else {  // pathological bucket: direct scatter
        for (int i = t; i < size; i += 256) {
            u64 p = bin[src0 + i];
            int pos = base + atomicAdd(&cur[(int)(p >> 32) - d0], 1);
            csr[pos] = (int)(unsigned)p;
        }
    }
}

// ---------------- Layer 1 GEMM via MFMA -> int8 half-tables + scales + attn dots ----
// (structure verified R9/R10) block = 256 thr, tile 64 nodes x 64 ch, K=256.
template <bool F32>
__global__ __launch_bounds__(256) void gemm1(
    const void* __restrict__ x, const void* __restrict__ W1,
    const void* __restrict__ as1, const void* __restrict__ ad1,
    const int* __restrict__ flags, signed char* __restrict__ xqA,
    signed char* __restrict__ xqB, float* __restrict__ sc2,
    float* __restrict__ asrc, float* __restrict__ adst) {
    if (flags[0] != (F32 ? 1 : 0)) return;
    __shared__ unsigned short af[8 * 64 * FR_W];   // aliased as f32 tile later
    __shared__ unsigned short wb[8 * 64 * FR_W];
    __shared__ float scl[64];
    int t = threadIdx.x;
    int mb = blockIdx.x >> 1, nb = blockIdx.x & 1;
    int m0 = mb * 64, n0 = nb * 64;
#pragma unroll
    for (int i = 0; i < 16; i++) {
        int slot = i * 256 + t;
        int mi = slot >> 6, k4 = (slot & 63) * 4;
        float4 v = make_float4(0.f, 0.f, 0.f, 0.f);
        if (m0 + mi < NN) v = ldin4<F32>(x, (m0 + mi) * FIN + k4);
        ushort4 o;
        o.x = f2us(v.x); o.y = f2us(v.y); o.z = f2us(v.z); o.w = f2us(v.w);
        *(ushort4*)&af[((k4 >> 5) * 64 + mi) * FR_W + (k4 & 31)] = o;
    }
#pragma unroll
    for (int i = 0; i < 16; i++) {
        int k = i * 16 + (t >> 4);
        int ni = (t & 15) * 4;
        float4 v = ldin4<F32>(W1, k * HD + n0 + ni);
        int ks = k >> 5, kk = k & 31;
        wb[(ks * 64 + ni + 0) * FR_W + kk] = f2us(v.x);
        wb[(ks * 64 + ni + 1) * FR_W + kk] = f2us(v.y);
        wb[(ks * 64 + ni + 2) * FR_W + kk] = f2us(v.z);
        wb[(ks * 64 + ni + 3) * FR_W + kk] = f2us(v.w);
    }
    __syncthreads();
    int w = t >> 6, lane = t & 63;
    int col = lane & 15, q = lane >> 4;
    floatx4 dacc[4];
#pragma unroll
    for (int mt = 0; mt < 4; mt++) { dacc[mt].x = 0.f; dacc[mt].y = 0.f; dacc[mt].z = 0.f; dacc[mt].w = 0.f; }
#pragma unroll
    for (int ks = 0; ks < 8; ks++) {
        short8 bf = *(const short8*)&wb[(ks * 64 + w * 16 + col) * FR_W + q * 8];
#pragma unroll
        for (int mt = 0; mt < 4; mt++) {
            short8 afr = *(const short8*)&af[(ks * 64 + mt * 16 + col) * FR_W + q * 8];
            dacc[mt] = __builtin_amdgcn_mfma_f32_16x16x32_bf16(afr, bf, dacc[mt], 0, 0, 0);
        }
    }
    __syncthreads();                 // all af reads done -> safe to alias
    float* fw = (float*)af;          // [64][FW_W] f32 tile
#pragma unroll
    for (int mt = 0; mt < 4; mt++) {
#pragma unroll
        for (int r = 0; r < 4; r++) {
            int nloc = mt * 16 + q * 4 + r;
            fw[nloc * FW_W + w * 16 + col] = dacc[mt][r];
        }
    }
    __syncthreads();
    {
        int node = t >> 2, part = t & 3;
        float amax = 0.f;
#pragma unroll
        for (int c = 0; c < 16; c++) amax = fmaxf(amax, fabsf(fw[node * FW_W + part * 16 + c]));
        amax = fmaxf(amax, __shfl_xor(amax, 1));
        amax = fmaxf(amax, __shfl_xor(amax, 2));
        if (part == 0) {
            scl[node] = (amax > 0.f) ? 127.f / amax : 0.f;
            if (m0 + node < NN) sc2[(m0 + node) * 2 + nb] = amax * (1.f / 127.f);
        }
    }
    __syncthreads();
    {
        int node = t >> 2, part = t & 3;
        if (m0 + node < NN) {
            float inv = scl[node];
            unsigned dw[4];
#pragma unroll
            for (int g = 0; g < 4; g++) {
                unsigned pk = 0;
#pragma unroll
                for (int j = 0; j < 4; j++) {
                    float v = fw[node * FW_W + part * 16 + g * 4 + j];
                    int qi = (int)rintf(v * inv);
                    qi = min(127, max(-127, qi));
                    pk |= ((unsigned)(qi & 255)) << (8 * j);
                }
                dw[g] = pk;
            }
            signed char* xqH = nb ? xqB : xqA;
            *(uint4*)&xqH[(m0 + node) * 64 + part * 16] = make_uint4(dw[0], dw[1], dw[2], dw[3]);
        }
    }
    {
        int node = t >> 2, hh = (t >> 1) & 1, half = t & 1;
        if (m0 + node < NN) {
            float s = 0.f, dd = 0.f;
            int cb = hh * 32 + half * 16;
#pragma unroll
            for (int c = 0; c < 16; c++) {
                float xv = fw[node * FW_W + cb + c];
                s  += xv * ldin<F32>(as1, n0 + cb + c);
                dd += xv * ldin<F32>(ad1, n0 + cb + c);
            }
            s  += __shfl_xor(s, 1);
            dd += __shfl_xor(dd, 1);
            if (half == 0) {
                int head = nb * 2 + hh;
                asrc[(m0 + node) * NH + head] = s;
                adst[(m0 + node) * NH + head] = dd;
            }
        }
    }
}

// ---------------- Layer 1 aggregate, one 64-ch half: wave-per-dst, barrier-free ----
// 4 dst / 256-thr block; per 32-edge chunk the wave computes 32x2 exp-weights in
// registers (lane = edge*2 + localhead) and redistributes via ds_bpermute executed
// in uniform control flow. Gather: 8 lanes x uint2 = one 64B line per edge.
// Output: h half-row (bias+ReLU) as bf16.
template <bool F32, int HALF>
__global__ __launch_bounds__(256) void nodeAgg(
    const int* __restrict__ rp, const int* __restrict__ cs,
    const float* __restrict__ asrc, const float* __restrict__ adst,
    const signed char* __restrict__ xqH, const float* __restrict__ sc2,
    const void* __restrict__ b1, const int* __restrict__ flags,
    unsigned short* __restrict__ hH) {
    if (flags[0] != (F32 ? 1 : 0)) return;
    int t = threadIdx.x, wv = t >> 6, lane = t & 63;
    int d = blockIdx.x * 4 + wv;
    int beg = rp[d], end = rp[d + 1];
    int eloc = lane >> 1, h = lane & 1;            // weight-phase role
    int cg = lane & 7, eo = lane >> 3, hl = cg >> 2; // gather-phase role
    float adw = adst[d * NH + HALF * 2 + h];
    const unsigned* xqu = (const unsigned*)xqH;
    float acc[8];
#pragma unroll
    for (int j = 0; j < 8; j++) acc[j] = 0.f;
    float wacc = 0.f;
    for (int ch = beg; ch < end; ch += 32) {
        int idx = ch + eloc;
        float wsc = 0.f;
        int s = 0;
        if (idx < end) {
            s = cs[idx];
            float wval = __expf(fminf(lrelu(asrc[s * NH + HALF * 2 + h] + adw), 80.f));
            wacc += wval;
            wsc = wval * sc2[s * 2 + HALF];
        }
        int m = min(32, end - ch);
        int rounds = (m + 7) >> 3;
        for (int r = 0; r < rounds; r++) {
            int e = eo + r * 8;                      // <= 31 always
            float we = bpermf(e * 2 + hl, wsc);      // uniform flow: all lanes active
            int s2 = bpermi(e * 2, s);
            if (e < m) {
                uint2 u = *(const uint2*)&xqu[s2 * 16 + cg * 2];
                acc[0] += we * sb2f(u.x, 0);
                acc[1] += we * sb2f(u.x, 8);
                acc[2] += we * sb2f(u.x, 16);
                acc[3] += we * sb2f(u.x, 24);
                acc[4] += we * sb2f(u.y, 0);
                acc[5] += we * sb2f(u.y, 8);
                acc[6] += we * sb2f(u.y, 16);
                acc[7] += we * sb2f(u.y, 24);
            }
        }
    }
    // reduce acc over eo (lane bits 3..5); wacc over edge bits (1..5)
#pragma unroll
    for (int j = 0; j < 8; j++) {
        acc[j] += __shfl_xor(acc[j], 8);
        acc[j] += __shfl_xor(acc[j], 16);
        acc[j] += __shfl_xor(acc[j], 32);
    }
    wacc += __shfl_xor(wacc, 2);
    wacc += __shfl_xor(wacc, 4);
    wacc += __shfl_xor(wacc, 8);
    wacc += __shfl_xor(wacc, 16);
    wacc += __shfl_xor(wacc, 32);
    float ws0 = __shfl(wacc, 0), ws1 = __shfl(wacc, 1);
    if (eo == 0) {                                   // lanes 0..7 hold final 8 ch each
        float rw = 1.f / (hl ? ws1 : ws0);
        unsigned pk[4];
#pragma unroll
        for (int g = 0; g < 4; g++) {
            float v0 = fmaxf(acc[2 * g]     * rw + ldin<F32>(b1, HALF * 64 + cg * 8 + 2 * g), 0.f);
            float v1 = fmaxf(acc[2 * g + 1] * rw + ldin<F32>(b1, HALF * 64 + cg * 8 + 2 * g + 1), 0.f);
            pk[g] = ((unsigned)f2us(v1) << 16) | f2us(v0);
        }
        *(uint4*)&hH[(size_t)d * 64 + cg * 8] = make_uint4(pk[0], pk[1], pk[2], pk[3]);
    }
}

// ---------------- hw2 = h @ W2 + layer-2 attention dots (16 dst / 256-thr block) ----
template <bool F32>
__global__ __launch_bounds__(256) void nodeW(
    const unsigned short* __restrict__ hA, const unsigned short* __restrict__ hB,
    const void* __restrict__ W2, const void* __restrict__ as2, const void* __restrict__ ad2,
    const int* __restrict__ flags, float* __restrict__ hw2,
    float* __restrict__ asrc2, float* __restrict__ adst2) {
    if (flags[0] != (F32 ? 1 : 0)) return;
    __shared__ float hs[16][132];
    __shared__ float w2s[HD * NC];
    int t = threadIdx.x;
    int dst0 = blockIdx.x * 16;
    // stage W2 (8KB) and the 16-node h tile
    for (int i = t; i < HD * NC / 4; i += 256)
        *(float4*)&w2s[i * 4] = ldin4<F32>(W2, i * 4);
    {
        int dn = t >> 4, oct = t & 15;
        uint4 u = (oct < 8) ? ((const uint4*)hA)[(size_t)(dst0 + dn) * 8 + oct]
                            : ((const uint4*)hB)[(size_t)(dst0 + dn) * 8 + (oct - 8)];
        float* hp = &hs[dn][oct * 8];
        hp[0] = us2f((unsigned short)(u.x & 0xffff)); hp[1] = us2f((unsigned short)(u.x >> 16));
        hp[2] = us2f((unsigned short)(u.y & 0xffff)); hp[3] = us2f((unsigned short)(u.y >> 16));
        hp[4] = us2f((unsigned short)(u.z & 0xffff)); hp[5] = us2f((unsigned short)(u.z >> 16));
        hp[6] = us2f((unsigned short)(u.w & 0xffff)); hp[7] = us2f((unsigned short)(u.w >> 16));
    }
    __syncthreads();
    int ln = t >> 4, j = t & 15;
    float acc = 0.f;
#pragma unroll 8
    for (int k = 0; k < HD; k++) acc += hs[ln][k] * w2s[k * NC + j];
    hw2[(dst0 + ln) * NC + j] = acc;
    float a2s = acc * ldin<F32>(as2, j);
    float a2d = acc * ldin<F32>(ad2, j);
#pragma unroll
    for (int off = 8; off; off >>= 1) {
        a2s += __shfl_xor(a2s, off, 16);
        a2d += __shfl_xor(a2d, off, 16);
    }
    if (j == 0) { asrc2[dst0 + ln] = a2s; adst2[dst0 + ln] = a2d; }
}

// ---------------- Layer 2 fused: vec4-gather softmax-aggregate + bias + log_softmax ----
template <bool F32>
__global__ __launch_bounds__(64) void node2(
    const int* __restrict__ rp, const int* __restrict__ cs,
    const float* __restrict__ asrc2, const float* __restrict__ adst2,
    const float* __restrict__ hw2, const void* __restrict__ b2,
    const int* __restrict__ flags, void* __restrict__ out) {
    if (flags[0] != (F32 ? 1 : 0)) return;
    int d = blockIdx.x, t = threadIdx.x;
    int beg = rp[d], end = rp[d + 1];
    float ad = adst2[d];
    __shared__ float sw2[64];
    __shared__ int   ss2[64];
    int q = t & 3, eo = t >> 2;
    float4 acc = make_float4(0.f, 0.f, 0.f, 0.f);
    float wsum = 0.f;
    for (int chb = beg; chb < end; chb += 64) {
        __syncthreads();
        int ec = chb + t;
        float w = 0.f;
        int s = 0;
        if (ec < end) {
            s = cs[ec];
            w = __expf(fminf(lrelu(asrc2[s] + ad), 80.f));
        }
        sw2[t] = w;
        ss2[t] = s;
        __syncthreads();
        int m = min(64, end - chb);
        for (int e = eo; e < m; e += 16) {
            float we = sw2[e];
            float4 v = *(const float4*)&hw2[ss2[e] * NC + q * 4];
            acc.x += we * v.x; acc.y += we * v.y;
            acc.z += we * v.z; acc.w += we * v.w;
            wsum += we;
        }
    }
#pragma unroll
    for (int off = 4; off < 64; off <<= 1) {
        acc.x += __shfl_xor(acc.x, off);
        acc.y += __shfl_xor(acc.y, off);
        acc.z += __shfl_xor(acc.z, off);
        acc.w += __shfl_xor(acc.w, off);
        wsum  += __shfl_xor(wsum, off);
    }
    float rw = 1.f / wsum;
    float v0 = acc.x * rw + ldin<F32>(b2, q * 4 + 0);
    float v1 = acc.y * rw + ldin<F32>(b2, q * 4 + 1);
    float v2 = acc.z * rw + ldin<F32>(b2, q * 4 + 2);
    float v3 = acc.w * rw + ldin<F32>(b2, q * 4 + 3);
    float mx = fmaxf(fmaxf(v0, v1), fmaxf(v2, v3));
    mx = fmaxf(mx, __shfl_xor(mx, 1));
    mx = fmaxf(mx, __shfl_xor(mx, 2));
    float es = __expf(v0 - mx) + __expf(v1 - mx) + __expf(v2 - mx) + __expf(v3 - mx);
    es += __shfl_xor(es, 1);
    es += __shfl_xor(es, 2);
    float lse = mx + __logf(es);
    if (t < 4) {
        if (F32) {
            *(float4*)&((float*)out)[d * NC + q * 4] =
                make_float4(v0 - lse, v1 - lse, v2 - lse, v3 - lse);
        } else {
            bf16* o = (bf16*)out + d * NC + q * 4;
            o[0] = __float2bfloat16(v0 - lse); o[1] = __float2bfloat16(v1 - lse);
            o[2] = __float2bfloat16(v2 - lse); o[3] = __float2bfloat16(v3 - lse);
        }
    }
}

extern "C" void kernel_launch(void* const* d_in, const int* in_sizes, int n_in,
                              void* d_out, int out_size, void* d_ws, size_t ws_size,
                              hipStream_t stream) {
    const void* x   = d_in[0];
    const void* ei  = d_in[1];
    const void* W1  = d_in[2];
    const void* as1 = d_in[3];
    const void* ad1 = d_in[4];
    const void* b1  = d_in[5];
    const void* W2  = d_in[6];
    const void* as2 = d_in[7];
    const void* ad2 = d_in[8];
    const void* b2v = d_in[9];

    float* ws = (float*)d_ws;
    int* flags = (int*)(ws + OF_FLAGS);
    int* bcur  = (int*)(ws + OF_BCUR);
    int* bbase = (int*)(ws + OF_BBASE);
    int* rp    = (int*)(ws + OF_RP);
    u64* bin   = (u64*)(ws + OF_BIN);
    int* csr   = (int*)(ws + OF_CSR);
    signed char* xqA = (signed char*)(ws + OF_XQA);
    signed char* xqB = (signed char*)(ws + OF_XQB);
    unsigned short* hA = (unsigned short*)(ws + OF_HA);   // aliases bin (dead after csrB)
    unsigned short* hB = (unsigned short*)(ws + OF_HB);
    float* sc2   = ws + OF_SC;
    float* asrc1 = ws + OF_AS1;
    float* adst1 = ws + OF_AD1;
    float* hw2   = ws + OF_HW2;
    float* asrc2 = ws + OF_AS2;
    float* adst2 = ws + OF_AD2;

    detect<<<1, 256, 0, stream>>>(x, ei, flags, bcur);
    binScatter<<<(E2 + CH2 - 1) / CH2, 256, 0, stream>>>(ei, flags, bcur, bin);
    bucketScan<<<1, K, 0, stream>>>(bcur, bbase);
    csrB<<<K, 256, 0, stream>>>(bin, bbase, rp, csr);

    const int GB = ((NN + 63) / 64) * 2;   // 782 m-blocks x 2 n-blocks = 1564
    gemm1<true><<<GB, 256, 0, stream>>>(x, W1, as1, ad1, flags, xqA, xqB, sc2, asrc1, adst1);
    nodeAgg<true, 0><<<NN / 4, 256, 0, stream>>>(rp, csr, asrc1, adst1, xqA, sc2, b1, flags, hA);
    nodeAgg<true, 1><<<NN / 4, 256, 0, stream>>>(rp, csr, asrc1, adst1, xqB, sc2, b1, flags, hB);
    nodeW<true><<<NN / 16, 256, 0, stream>>>(hA, hB, W2, as2, ad2, flags, hw2, asrc2, adst2);
    node2<true><<<NN, 64, 0, stream>>>(rp, csr, asrc2, adst2, hw2, b2v, flags, d_out);
}

// Round 12
// 295.300 us; speedup vs baseline: 1.1000x; 1.1000x over previous
//
#include <hip/hip_runtime.h>
#include <hip/hip_bf16.h>

typedef __hip_bfloat16 bf16;
typedef long long i64;
typedef unsigned long long u64;
typedef __attribute__((ext_vector_type(8))) short short8;
typedef __attribute__((ext_vector_type(4))) float floatx4;

#define NN    50000
#define EE    1600000
#define E2    1650000     // EE + NN self loops
#define FIN   256
#define HD    128         // HEADS*HID
#define NH    4
#define NC    16
#define SLOPE 0.2f
#define K     128         // dst buckets
#define DPB   391         // nodes per bucket (128*391 = 50048 >= NN)
#define CAPB  16384       // per-bucket bin capacity (mean 12891, +30 sigma)
#define CAP   15360       // LDS csr buffer per bucket
#define CH2   2048        // edges per binScatter chunk (8 consecutive per thread)

#define KS_S  2312        // A-frag ks-block stride in shorts (64*36+8): 16B-aligned,
                          // bank offset 4 per ks -> <=4-way staging stores (was 8-way)

// ---- workspace 4-byte-unit offsets (total ~8.9M dwords = 35.6 MB; 61.6 proven safe) ----
#define OF_FLAGS 0            // 16 ints
#define OF_BCUR  16           // K ints
#define OF_BBASE 144          // K+1 ints (pad to 280)
#define OF_RP    280          // NN+1 ints (pad to 50284)
#define OF_W1T   50284        // bf16[8*128*32] = 16384 dwords (16B aligned)
#define OF_BIN   66668        // u64[K*CAPB] (8B aligned: even)
#define OF_CSR   4260972      // E2 ints
#define OF_XQ    5910972      // int8[NN*128] = 1.6M dwords (16B aligned)
#define OF_SC    7510972      // f32[NN*2]
#define OF_AS1   7610972      // NN*NH f32
#define OF_AD1   7810972      // NN*NH f32
#define OF_HW2   8010972      // NN*NC f32 (16B aligned)
#define OF_AS2   8810972      // NN f32
#define OF_AD2   8860972      // NN f32

__device__ __forceinline__ float b2f(bf16 v) { return __bfloat162float(v); }
__device__ __forceinline__ float us2f(unsigned short u) {
    return __uint_as_float(((unsigned)u) << 16);
}
__device__ __forceinline__ unsigned short f2us(float f) {   // RNE f32->bf16
    unsigned u = __float_as_uint(f);
    return (unsigned short)((u + 0x7fffu + ((u >> 16) & 1u)) >> 16);
}
__device__ __forceinline__ float lrelu(float v) { return v > 0.f ? v : SLOPE * v; }
__device__ __forceinline__ float sb2f(unsigned u, int sh) {   // signed byte -> float
    return (float)((int)(u << (24 - sh)) >> 24);
}
// f32 epilogue tile index: [node][part=ch>>5][33] -> bank = (node*4+part+c)%32 (2-way max)
__device__ __forceinline__ int fwi(int node, int ch) {
    return node * 132 + (ch >> 5) * 33 + (ch & 31);
}

template <bool F32>
__device__ __forceinline__ float ldin(const void* p, int i) {
    if (F32) return ((const float*)p)[i];
    return b2f(((const bf16*)p)[i]);
}
template <bool F32>
__device__ __forceinline__ float4 ldin4(const void* p, int i) {
    if (F32) return *(const float4*)((const float*)p + i);
    ushort4 u = *(const ushort4*)((const unsigned short*)p + i);
    float4 r;
    r.x = us2f(u.x); r.y = us2f(u.y); r.z = us2f(u.z); r.w = us2f(u.w);
    return r;
}

__device__ __forceinline__ void edge_sd(const void* ei, int f64, int e, int& s, int& d) {
    if (e >= EE) { s = e - EE; d = s; return; }
    if (f64) {
        s = (int)((const i64*)ei)[e];
        d = (int)((const i64*)ei)[EE + e];
    } else {
        s = ((const int*)ei)[e];
        d = ((const int*)ei)[EE + e];
    }
    s = min(max(s, 0), NN - 1);
    d = min(max(d, 0), NN - 1);
}

// ---------------- detect (proven: picks f32/i32) + bcur init ----------------
__global__ void detect(const void* x, const void* ei, int* flags, int* bcur) {
    __shared__ int cnt[2];
    int t = threadIdx.x;
    if (t < K) bcur[t] = t * CAPB;
    if (t == 0) { cnt[0] = 0; cnt[1] = 0; }
    __syncthreads();
    const unsigned short* xb = (const unsigned short*)x;
    int c0 = 0;
    for (int i = t; i < 4096; i += 256) {
        float v = __uint_as_float(((unsigned)xb[2 * i]) << 16);
        if (!(fabsf(v) < 1e6f)) c0++;
    }
    const i64* e64 = (const i64*)ei;
    int c1 = 0;
    for (int i = t; i < 1024; i += 256) {
        i64 v = e64[i];
        if (v >= 0 && v < NN) c1++;
    }
    atomicAdd(&cnt[0], c0);
    atomicAdd(&cnt[1], c1);
    __syncthreads();
    if (t == 0) {
        flags[0] = (cnt[0] > 400) ? 1 : 0;
        flags[1] = (cnt[1] >= 1000) ? 1 : 0;
    }
}

// ---------------- W1 -> bf16 fragment-ordered global table ----------------
// W1T[((k>>5)*128 + n)*32 + (k&31)] = bf16(W1[k][n]); 64 KB, L2-resident.
template <bool F32>
__global__ void trW(const void* __restrict__ W1, const int* __restrict__ flags,
                    unsigned short* __restrict__ w1t) {
    if (flags[0] != (F32 ? 1 : 0)) return;
    int t = blockIdx.x * 256 + threadIdx.x;      // 32 blocks x 256 = 8192 = 256*128/4
    int k = t >> 5, n4 = (t & 31) * 4;
    float4 v = ldin4<F32>(W1, k * HD + n4);
    int ks = k >> 5, kk = k & 31;
    w1t[((ks * HD + n4 + 0) * 32) + kk] = f2us(v.x);
    w1t[((ks * HD + n4 + 1) * 32) + kk] = f2us(v.y);
    w1t[((ks * HD + n4 + 2) * 32) + kk] = f2us(v.z);
    w1t[((ks * HD + n4 + 3) * 32) + kk] = f2us(v.w);
}

// single-pass scatter: 8 consecutive edges/thread, int4 edge loads, LDS-histogram ranks
__global__ __launch_bounds__(256) void binScatter(const void* __restrict__ ei,
                                                  const int* __restrict__ flags,
                                                  int* __restrict__ bcur,
                                                  u64* __restrict__ bin) {
    __shared__ int h[K], res[K];
    int t = threadIdx.x;
    int base = blockIdx.x * CH2 + t * 8;
    if (t < K) h[t] = 0;
    __syncthreads();
    int f64 = flags[1];
    int sv[8], dv[8], rk[8];
    int n_ = 0;
    if (!f64 && base + 8 <= EE) {
        const int* es = (const int*)ei;
        int4 a = *(const int4*)&es[base];
        int4 b = *(const int4*)&es[base + 4];
        int4 c = *(const int4*)&es[EE + base];
        int4 g = *(const int4*)&es[EE + base + 4];
        sv[0] = a.x; sv[1] = a.y; sv[2] = a.z; sv[3] = a.w;
        sv[4] = b.x; sv[5] = b.y; sv[6] = b.z; sv[7] = b.w;
        dv[0] = c.x; dv[1] = c.y; dv[2] = c.z; dv[3] = c.w;
        dv[4] = g.x; dv[5] = g.y; dv[6] = g.z; dv[7] = g.w;
#pragma unroll
        for (int i = 0; i < 8; i++) {
            sv[i] = min(max(sv[i], 0), NN - 1);
            dv[i] = min(max(dv[i], 0), NN - 1);
        }
        n_ = 8;
    } else {
        for (int i = 0; i < 8; i++) {
            int e = base + i;
            if (e < E2) {
                int s, d; edge_sd(ei, f64, e, s, d);
                sv[n_] = s; dv[n_] = d; n_++;
            }
        }
    }
#pragma unroll 8
    for (int i = 0; i < n_; i++) rk[i] = atomicAdd(&h[dv[i] / DPB], 1);
    __syncthreads();
    if (t < K) res[t] = h[t] ? atomicAdd(&bcur[t], h[t]) : 0;
    __syncthreads();
#pragma unroll 8
    for (int i = 0; i < n_; i++) {
        int b = dv[i] / DPB;
        int pos = res[b] + rk[i];
        pos = min(pos, (b + 1) * CAPB - 1);   // overflow safety (never hit: +30 sigma)
        bin[pos] = (((u64)(unsigned)dv[i]) << 32) | (unsigned)sv[i];
    }
}

// exclusive scan of actual bucket sizes -> bbase (packed csr layout)
__global__ void bucketScan(const int* __restrict__ bcur, int* __restrict__ bbase) {
    __shared__ int sh[K];
    int t = threadIdx.x;
    int v = min(bcur[t] - t * CAPB, CAPB);
    sh[t] = v;
    __syncthreads();
    for (int off = 1; off < K; off <<= 1) {
        int u = (t >= off) ? sh[t - off] : 0;
        __syncthreads();
        sh[t] += u;
        __syncthreads();
    }
    bbase[t] = sh[t] - v;
    if (t == K - 1) bbase[K] = sh[K - 1];
}

// per-bucket local CSR: per-dst count -> scan -> rp + LDS scatter -> coalesced csr
__global__ __launch_bounds__(256) void csrB(const u64* __restrict__ bin,
                                            const int* __restrict__ bbase,
                                            int* __restrict__ rp, int* __restrict__ csr) {
    __shared__ int cnt[512];
    __shared__ int cur[DPB];
    __shared__ int buf[CAP];     // also reused as scan partials
    int b = blockIdx.x, t = threadIdx.x;
    int d0 = b * DPB;
    int nd = min(DPB, NN - d0);
    int src0 = b * CAPB;
    int base = bbase[b], size = bbase[b + 1] - base;
    cnt[t] = 0; cnt[t + 256] = 0;
    __syncthreads();
    for (int i = t; i < size; i += 256) {
        int d = (int)(bin[src0 + i] >> 32);
        atomicAdd(&cnt[d - d0], 1);
    }
    __syncthreads();
    int a0 = cnt[2 * t], a1 = cnt[2 * t + 1];
    int ps = a0 + a1;
    buf[t] = ps;
    __syncthreads();
    for (int off = 1; off < 256; off <<= 1) {
        int u = (t >= off) ? buf[t - off] : 0;
        __syncthreads();
        buf[t] += u;
        __syncthreads();
    }
    int ex = buf[t] - ps;
    __syncthreads();
    cnt[2 * t] = ex;
    cnt[2 * t + 1] = ex + a0;
    __syncthreads();
    for (int i = t; i < nd; i += 256) {
        rp[d0 + i] = base + cnt[i];
        cur[i] = cnt[i];
    }
    if (b == K - 1 && t == 0) rp[NN] = bbase[K];
    __syncthreads();
    if (size <= CAP) {
        for (int i = t; i < size; i += 256) {
            u64 p = bin[src0 + i];
            int pos = atomicAdd(&cur[(int)(p >> 32) - d0], 1);
            buf[pos] = (int)(unsigned)p;
        }
        __syncthreads();
        for (int i = t; i < size; i += 256) csr[base + i] = buf[i];
    } else {  // pathological bucket: direct scatter
        for (int i = t; i < size; i += 256) {
            u64 p = bin[src0 + i];
            int pos = base + atomicAdd(&cur[(int)(p >> 32) - d0], 1);
            csr[pos] = (int)(unsigned)p;
        }
    }
}

// ---------------- Layer 1 GEMM via MFMA (full-width tile) ----------------
// block = 256 thr (4 waves), tile 64 nodes x 128 channels, K=256; 782 blocks, x read once.
// A staged fragment-ordered in LDS (ks-stride KS_S: <=4-way store conflicts);
// B frags come straight from the L2-resident W1T table (no B LDS at all).
// Wave w owns channels w*32..+31 (2 n-tiles); mfma_f32_16x16x32_bf16 layouts verified R9/R10.
// Epilogue: head h == channels h*32..+31 == one thread's quarter -> dots shuffle-free.
template <bool F32>
__global__ __launch_bounds__(256) void gemm1(
    const void* __restrict__ x, const unsigned short* __restrict__ w1t,
    const void* __restrict__ as1, const void* __restrict__ ad1,
    const int* __restrict__ flags, signed char* __restrict__ xq, float* __restrict__ sc2,
    float* __restrict__ asrc, float* __restrict__ adst) {
    if (flags[0] != (F32 ? 1 : 0)) return;
    __shared__ unsigned short af[8 * KS_S];      // 36992 B; aliased as f32 tile after MFMA
    __shared__ float scl[128];                   // [node][half] quant scales
    int t = threadIdx.x;
    int m0 = blockIdx.x * 64;
    // ---- stage A: x[m0..+63][0..255] f32 -> bf16 frags af[ks][m][36] ----
#pragma unroll
    for (int i = 0; i < 16; i++) {
        int slot = i * 256 + t;
        int mi = slot >> 6, k4 = (slot & 63) * 4;
        float4 v = make_float4(0.f, 0.f, 0.f, 0.f);
        if (m0 + mi < NN) v = ldin4<F32>(x, (m0 + mi) * FIN + k4);
        ushort4 o;
        o.x = f2us(v.x); o.y = f2us(v.y); o.z = f2us(v.z); o.w = f2us(v.w);
        *(ushort4*)&af[(k4 >> 5) * KS_S + mi * 36 + (k4 & 31)] = o;
    }
    __syncthreads();
    int w = t >> 6, lane = t & 63;
    int col = lane & 15, q = lane >> 4;
    floatx4 acc[4][2];
#pragma unroll
    for (int mt = 0; mt < 4; mt++)
#pragma unroll
        for (int u = 0; u < 2; u++) { acc[mt][u].x = 0.f; acc[mt][u].y = 0.f; acc[mt][u].z = 0.f; acc[mt][u].w = 0.f; }
#pragma unroll
    for (int ks = 0; ks < 8; ks++) {
        short8 bf0 = *(const short8*)&w1t[(ks * HD + w * 32 + col) * 32 + q * 8];
        short8 bf1 = *(const short8*)&w1t[(ks * HD + w * 32 + 16 + col) * 32 + q * 8];
#pragma unroll
        for (int mt = 0; mt < 4; mt++) {
            short8 afr = *(const short8*)&af[ks * KS_S + (mt * 16 + col) * 36 + q * 8];
            acc[mt][0] = __builtin_amdgcn_mfma_f32_16x16x32_bf16(afr, bf0, acc[mt][0], 0, 0, 0);
            acc[mt][1] = __builtin_amdgcn_mfma_f32_16x16x32_bf16(afr, bf1, acc[mt][1], 0, 0, 0);
        }
    }
    __syncthreads();                 // all af reads done -> safe to alias
    float* fw = (float*)af;          // [64][4][33] f32 tile (33792 B)
#pragma unroll
    for (int mt = 0; mt < 4; mt++)
#pragma unroll
        for (int u = 0; u < 2; u++)
#pragma unroll
            for (int r = 0; r < 4; r++) {
                int node = mt * 16 + q * 4 + r;
                fw[fwi(node, w * 32 + u * 16 + col)] = acc[mt][u][r];
            }
    __syncthreads();
    // ---- scales: thread = (node t>>2, part t&3 = head = 32-ch quarter); half = part>>1 ----
    int node = t >> 2, part = t & 3;
    {
        float amax = 0.f;
#pragma unroll
        for (int c = 0; c < 32; c++) amax = fmaxf(amax, fabsf(fw[fwi(node, part * 32 + c)]));
        amax = fmaxf(amax, __shfl_xor(amax, 1));     // combine parts {0,1} / {2,3}
        if ((part & 1) == 0) {
            scl[node * 2 + (part >> 1)] = (amax > 0.f) ? 127.f / amax : 0.f;
            if (m0 + node < NN) sc2[(m0 + node) * 2 + (part >> 1)] = amax * (1.f / 127.f);
        }
    }
    __syncthreads();
    if (m0 + node < NN) {
        // ---- quantize my 32 channels (two uint4 = 32 B; row fully coalesced) ----
        float inv = scl[node * 2 + (part >> 1)];
        unsigned dw[8];
#pragma unroll
        for (int g = 0; g < 8; g++) {
            unsigned pk = 0;
#pragma unroll
            for (int j = 0; j < 4; j++) {
                float v = fw[fwi(node, part * 32 + g * 4 + j)];
                int qi = (int)rintf(v * inv);
                qi = min(127, max(-127, qi));
                pk |= ((unsigned)(qi & 255)) << (8 * j);
            }
            dw[g] = pk;
        }
        *(uint4*)&xq[(m0 + node) * HD + part * 32]      = make_uint4(dw[0], dw[1], dw[2], dw[3]);
        *(uint4*)&xq[(m0 + node) * HD + part * 32 + 16] = make_uint4(dw[4], dw[5], dw[6], dw[7]);
        // ---- attention dots for head = part (no shuffles needed) ----
        float s = 0.f, dd = 0.f;
#pragma unroll
        for (int c = 0; c < 32; c++) {
            float xv = fw[fwi(node, part * 32 + c)];
            s  += xv * ldin<F32>(as1, part * 32 + c);
            dd += xv * ldin<F32>(ad1, part * 32 + c);
        }
        asrc[(m0 + node) * NH + part] = s;
        adst[(m0 + node) * NH + part] = dd;
    }
}

// ---------------- Layer 1 fused (R10-proven): int8-gather + bias/ReLU + h@W2 + L2 dots ----
template <bool F32>
__global__ __launch_bounds__(128) void node1(
    const int* __restrict__ rp, const int* __restrict__ cs,
    const float* __restrict__ asrc, const float* __restrict__ adst,
    const signed char* __restrict__ xq, const float* __restrict__ sc2,
    const void* __restrict__ b1, const void* __restrict__ W2,
    const void* __restrict__ as2, const void* __restrict__ ad2,
    const int* __restrict__ flags, float* __restrict__ hw2,
    float* __restrict__ asrc2, float* __restrict__ adst2) {
    if (flags[0] != (F32 ? 1 : 0)) return;
    int d = blockIdx.x, t = threadIdx.x;
    int beg = rp[d], end = rp[d + 1];
    __shared__ float sw[32][4];
    __shared__ int   ss[32];
    __shared__ float red[2][HD];
    __shared__ float wv[2][4];
    __shared__ float hs[HD];
    __shared__ float l2[32];
    int hw_ = t & 3;
    float adw = adst[d * NH + hw_];
    int cg = t & 15, eo = t >> 4, head = cg >> 2;
    float acc[8];
#pragma unroll
    for (int j = 0; j < 8; j++) acc[j] = 0.f;
    float wacc = 0.f;
    const unsigned* xqu = (const unsigned*)xq;
    for (int chb = beg; chb < end; chb += 32) {
        __syncthreads();
        int ec = chb + (t >> 2);
        float w = 0.f, wsc = 0.f;
        int s = 0;
        if (ec < end) {
            s = cs[ec];
            w = __expf(fminf(lrelu(asrc[s * NH + hw_] + adw), 80.f));
            wsc = w * sc2[s * 2 + (hw_ >> 1)];
        }
        sw[t >> 2][hw_] = wsc;         // addr == t: conflict-free
        if (hw_ == 0) ss[t >> 2] = s;
        wacc += w;
        __syncthreads();
        int m = min(32, end - chb);
        for (int e = eo; e < m; e += 8) {
            float we = sw[e][head];
            int s2 = ss[e];
            uint2 u = *(const uint2*)&xqu[s2 * 32 + cg * 2];
            acc[0] += we * sb2f(u.x, 0);
            acc[1] += we * sb2f(u.x, 8);
            acc[2] += we * sb2f(u.x, 16);
            acc[3] += we * sb2f(u.x, 24);
            acc[4] += we * sb2f(u.y, 0);
            acc[5] += we * sb2f(u.y, 8);
            acc[6] += we * sb2f(u.y, 16);
            acc[7] += we * sb2f(u.y, 24);
        }
    }
    // wsum reduce: over e-lanes (bits 2..5 of lane), per head
    wacc += __shfl_xor(wacc, 4);
    wacc += __shfl_xor(wacc, 8);
    wacc += __shfl_xor(wacc, 16);
    wacc += __shfl_xor(wacc, 32);
    int wid = t >> 6, lane = t & 63;
    if (lane < 4) wv[wid][lane] = wacc;
    // acc reduce over eo within wave, then cross-wave
#pragma unroll
    for (int j = 0; j < 8; j++) {
        acc[j] += __shfl_xor(acc[j], 16);
        acc[j] += __shfl_xor(acc[j], 32);
    }
    if (lane < 16) {
#pragma unroll
        for (int j = 0; j < 8; j++) red[wid][lane * 8 + j] = acc[j];
    }
    __syncthreads();
    float tot = red[0][t] + red[1][t];
    float wt  = wv[0][t >> 5] + wv[1][t >> 5];
    hs[t] = fmaxf(tot / wt + ldin<F32>(b1, t), 0.f);
    __syncthreads();
    int j = t & 15, g = t >> 4;
    float p = 0.f;
#pragma unroll
    for (int k = 0; k < 16; k++) p += hs[g * 16 + k] * ldin<F32>(W2, (g * 16 + k) * NC + j);
    p += __shfl_xor(p, 16, 64);
    p += __shfl_xor(p, 32, 64);
    if ((t & 63) < 16) l2[(t >> 6) * 16 + j] = p;
    __syncthreads();
    if (t < 16) {
        float hw = l2[t] + l2[16 + t];
        hw2[d * NC + t] = hw;
        float a2s = hw * ldin<F32>(as2, t);
        float a2d = hw * ldin<F32>(ad2, t);
#pragma unroll
        for (int off = 8; off; off >>= 1) {
            a2s += __shfl_xor(a2s, off, 16);
            a2d += __shfl_xor(a2d, off, 16);
        }
        if (t == 0) { asrc2[d] = a2s; adst2[d] = a2d; }
    }
}

// ---------------- Layer 2 fused: vec4-gather softmax-aggregate + bias + log_softmax ----
template <bool F32>
__global__ __launch_bounds__(64) void node2(
    const int* __restrict__ rp, const int* __restrict__ cs,
    const float* __restrict__ asrc2, const float* __restrict__ adst2,
    const float* __restrict__ hw2, const void* __restrict__ b2,
    const int* __restrict__ flags, void* __restrict__ out) {
    if (flags[0] != (F32 ? 1 : 0)) return;
    int d = blockIdx.x, t = threadIdx.x;
    int beg = rp[d], end = rp[d + 1];
    float ad = adst2[d];
    __shared__ float sw2[64];
    __shared__ int   ss2[64];
    int q = t & 3, eo = t >> 2;
    float4 acc = make_float4(0.f, 0.f, 0.f, 0.f);
    float wsum = 0.f;
    for (int chb = beg; chb < end; chb += 64) {
        __syncthreads();
        int ec = chb + t;
        float w = 0.f;
        int s = 0;
        if (ec < end) {
            s = cs[ec];
            w = __expf(fminf(lrelu(asrc2[s] + ad), 80.f));
        }
        sw2[t] = w;
        ss2[t] = s;
        __syncthreads();
        int m = min(64, end - chb);
        for (int e = eo; e < m; e += 16) {
            float we = sw2[e];
            float4 v = *(const float4*)&hw2[ss2[e] * NC + q * 4];
            acc.x += we * v.x; acc.y += we * v.y;
            acc.z += we * v.z; acc.w += we * v.w;
            wsum += we;
        }
    }
#pragma unroll
    for (int off = 4; off < 64; off <<= 1) {
        acc.x += __shfl_xor(acc.x, off);
        acc.y += __shfl_xor(acc.y, off);
        acc.z += __shfl_xor(acc.z, off);
        acc.w += __shfl_xor(acc.w, off);
        wsum  += __shfl_xor(wsum, off);
    }
    float rw = 1.f / wsum;
    float v0 = acc.x * rw + ldin<F32>(b2, q * 4 + 0);
    float v1 = acc.y * rw + ldin<F32>(b2, q * 4 + 1);
    float v2 = acc.z * rw + ldin<F32>(b2, q * 4 + 2);
    float v3 = acc.w * rw + ldin<F32>(b2, q * 4 + 3);
    float mx = fmaxf(fmaxf(v0, v1), fmaxf(v2, v3));
    mx = fmaxf(mx, __shfl_xor(mx, 1));
    mx = fmaxf(mx, __shfl_xor(mx, 2));
    float es = __expf(v0 - mx) + __expf(v1 - mx) + __expf(v2 - mx) + __expf(v3 - mx);
    es += __shfl_xor(es, 1);
    es += __shfl_xor(es, 2);
    float lse = mx + __logf(es);
    if (t < 4) {
        if (F32) {
            *(float4*)&((float*)out)[d * NC + q * 4] =
                make_float4(v0 - lse, v1 - lse, v2 - lse, v3 - lse);
        } else {
            bf16* o = (bf16*)out + d * NC + q * 4;
            o[0] = __float2bfloat16(v0 - lse); o[1] = __float2bfloat16(v1 - lse);
            o[2] = __float2bfloat16(v2 - lse); o[3] = __float2bfloat16(v3 - lse);
        }
    }
}

extern "C" void kernel_launch(void* const* d_in, const int* in_sizes, int n_in,
                              void* d_out, int out_size, void* d_ws, size_t ws_size,
                              hipStream_t stream) {
    const void* x   = d_in[0];
    const void* ei  = d_in[1];
    const void* W1  = d_in[2];
    const void* as1 = d_in[3];
    const void* ad1 = d_in[4];
    const void* b1  = d_in[5];
    const void* W2  = d_in[6];
    const void* as2 = d_in[7];
    const void* ad2 = d_in[8];
    const void* b2v = d_in[9];

    float* ws = (float*)d_ws;
    int* flags = (int*)(ws + OF_FLAGS);
    int* bcur  = (int*)(ws + OF_BCUR);
    int* bbase = (int*)(ws + OF_BBASE);
    int* rp    = (int*)(ws + OF_RP);
    unsigned short* w1t = (unsigned short*)(ws + OF_W1T);
    u64* bin   = (u64*)(ws + OF_BIN);
    int* csr   = (int*)(ws + OF_CSR);
    signed char* xq = (signed char*)(ws + OF_XQ);
    float* sc2   = ws + OF_SC;
    float* asrc1 = ws + OF_AS1;
    float* adst1 = ws + OF_AD1;
    float* hw2   = ws + OF_HW2;
    float* asrc2 = ws + OF_AS2;
    float* adst2 = ws + OF_AD2;

    detect<<<1, 256, 0, stream>>>(x, ei, flags, bcur);
    trW<true><<<32, 256, 0, stream>>>(W1, flags, w1t);
    binScatter<<<(E2 + CH2 - 1) / CH2, 256, 0, stream>>>(ei, flags, bcur, bin);
    bucketScan<<<1, K, 0, stream>>>(bcur, bbase);
    csrB<<<K, 256, 0, stream>>>(bin, bbase, rp, csr);

    const int GB = (NN + 63) / 64;   // 782 full-width blocks; x read exactly once
    gemm1<true><<<GB, 256, 0, stream>>>(x, w1t, as1, ad1, flags, xq, sc2, asrc1, adst1);
    node1<true><<<NN, 128, 0, stream>>>(rp, csr, asrc1, adst1, xq, sc2, b1, W2, as2, ad2,
                                        flags, hw2, asrc2, adst2);
    node2<true><<<NN, 64, 0, stream>>>(rp, csr, asrc2, adst2, hw2, b2v, flags, d_out);
}